// Round 1
// baseline (4065.640 us; speedup 1.0000x reference)
//
#include <hip/hip_runtime.h>

// Model dims
#define BB 128
#define TT 64
#define EE 512
#define HH 512
#define VV 10000
#define FIN 2048

typedef __attribute__((ext_vector_type(4))) float f32x4_t;
typedef __attribute__((ext_vector_type(8))) short s16x8_t;

__device__ __forceinline__ unsigned short f2bf(float x) {
    unsigned int u = __float_as_uint(x);
    unsigned int r = (u + 0x7fffu + ((u >> 16) & 1u)) >> 16;
    return (unsigned short)r;
}

// ---------------- generic fp32 GEMM: C[M,N] = A[M,K] @ B[N,K]^T + epilogue ----------
// grid = (N/32, M/32), block = (16,16). All of M,N multiples of 32; K multiple of 32.
// mode 0: v += bias?bias[c] + base?base[r*ldbase+c]
// mode 1: v += (c<512) ? base[r*512+c] : bias[c-512]   (fused Lh|gh epilogue)
__global__ __launch_bounds__(256) void gemm32(
    const float* __restrict__ A, int lda,
    const float* __restrict__ Bw, int ldb, int bofs,
    float* __restrict__ C, int ldc, int K,
    const float* __restrict__ bias,
    const float* __restrict__ base, int ldbase, int mode)
{
    __shared__ float As[32][34];
    __shared__ float Bs[32][34];
    const int tx = threadIdx.x, ty = threadIdx.y;
    const int tid = ty * 16 + tx;
    const int m0 = blockIdx.y * 32, n0 = blockIdx.x * 32;
    const int lr = tid >> 3, lc = (tid & 7) << 2;
    const float* ap = A + (size_t)(m0 + lr) * lda + lc;
    const float* bp = Bw + (size_t)(n0 + lr) * ldb + bofs + lc;
    float c00 = 0.f, c01 = 0.f, c10 = 0.f, c11 = 0.f;
    for (int kc = 0; kc < K; kc += 32) {
        float4 av = *(const float4*)(ap + kc);
        float4 bv = *(const float4*)(bp + kc);
        __syncthreads();
        As[lc + 0][lr] = av.x; As[lc + 1][lr] = av.y;
        As[lc + 2][lr] = av.z; As[lc + 3][lr] = av.w;
        Bs[lc + 0][lr] = bv.x; Bs[lc + 1][lr] = bv.y;
        Bs[lc + 2][lr] = bv.z; Bs[lc + 3][lr] = bv.w;
        __syncthreads();
#pragma unroll
        for (int kk = 0; kk < 32; kk++) {
            float2 a = *(const float2*)&As[kk][2 * ty];
            float2 b = *(const float2*)&Bs[kk][2 * tx];
            c00 = fmaf(a.x, b.x, c00); c01 = fmaf(a.x, b.y, c01);
            c10 = fmaf(a.y, b.x, c10); c11 = fmaf(a.y, b.y, c11);
        }
    }
    float cc[2][2] = {{c00, c01}, {c10, c11}};
    const int row = m0 + 2 * ty, col = n0 + 2 * tx;
#pragma unroll
    for (int i = 0; i < 2; i++)
#pragma unroll
        for (int j = 0; j < 2; j++) {
            int r = row + i, c = col + j;
            float v = cc[i][j];
            if (mode == 0) {
                if (bias) v += bias[c];
                if (base) v += base[(size_t)r * ldbase + c];
            } else {
                v += (c < 512) ? base[r * 512 + c] : bias[c - 512];
            }
            C[(size_t)r * ldc + c] = v;
        }
}

// ---------------- BatchNorm1d (training stats over B=128) --------------------------
__global__ __launch_bounds__(128) void bn_kernel(
    const float* __restrict__ f, const float* __restrict__ gamma,
    const float* __restrict__ beta, float* __restrict__ feats)
{
    int e = blockIdx.x, b = threadIdx.x;
    float v = f[b * EE + e];
    __shared__ float s1[128], s2[128];
    s1[b] = v; s2[b] = v * v;
    __syncthreads();
    for (int s = 64; s > 0; s >>= 1) {
        if (b < s) { s1[b] += s1[b + s]; s2[b] += s2[b + s]; }
        __syncthreads();
    }
    float mu = s1[0] * (1.f / 128.f);
    float var = s2[0] * (1.f / 128.f) - mu * mu;
    float inv = 1.f / sqrtf(var + 1e-5f);
    feats[b * EE + e] = gamma[e] * (v - mu) * inv + beta[e];
}

// ---------------- build X[t][b][:]: t=0 -> feats, else embed_W[cap[b][t-1]] --------
__global__ void build_x(const float* __restrict__ feats, const float* __restrict__ embW,
                        const int* __restrict__ cap, float* __restrict__ X)
{
    int id = blockIdx.x * 256 + threadIdx.x;   // 1,048,576 float4 slots
    int e4 = id & 127;
    int rem = id >> 7;
    int b = rem & 127;
    int t = rem >> 7;
    const float4* src;
    if (t == 0) src = (const float4*)(feats + b * EE) + e4;
    else        src = (const float4*)(embW + (size_t)cap[b * TT + t - 1] * EE) + e4;
    ((float4*)X)[(size_t)(t * BB + b) * 128 + e4] = *src;
}

// ---------------- weight packing -------------------------------------------------
__global__ void pack_wcat(const float* __restrict__ attnW, const float* __restrict__ Whh,
                          float* __restrict__ Wcat)
{
    int i = blockIdx.x * 256 + threadIdx.x;    // 1,048,576
    int j = i >> 9, k = i & 511;
    Wcat[i] = (j < 512) ? attnW[j * 1024 + 512 + k]
                        : Whh[(size_t)(j - 512) * 512 + k];
}

__global__ void transpose_wa(const float* __restrict__ combW, float* __restrict__ WaT)
{
    int i = blockIdx.x * 256 + threadIdx.x;    // 262,144: WaT[m][n] = comb_W[n][512+m]
    int m = i >> 9, n = i & 511;
    WaT[i] = combW[n * 1024 + 512 + m];
}

__global__ void cvt_bf16(const float* __restrict__ src, unsigned short* __restrict__ dst, int n)
{
    int i = blockIdx.x * 256 + threadIdx.x;
    if (i < n) dst[i] = f2bf(src[i]);
}

// ---------------- per-step: softmax over L row + applied = feats*aw ----------------
__global__ __launch_bounds__(256) void softmax_applied(
    const float* __restrict__ AB, const float* __restrict__ feats, float* __restrict__ APP)
{
    int b = blockIdx.x, tid = threadIdx.x;
    const float* L = AB + b * 2048;
    float v0 = L[tid], v1 = L[tid + 256];
    __shared__ float red[256];
    red[tid] = fmaxf(v0, v1);
    __syncthreads();
    for (int s = 128; s > 0; s >>= 1) {
        if (tid < s) red[tid] = fmaxf(red[tid], red[tid + s]);
        __syncthreads();
    }
    float mx = red[0];
    __syncthreads();
    float e0 = __expf(v0 - mx), e1 = __expf(v1 - mx);
    red[tid] = e0 + e1;
    __syncthreads();
    for (int s = 128; s > 0; s >>= 1) {
        if (tid < s) red[tid] += red[tid + s];
        __syncthreads();
    }
    float inv = 1.f / red[0];
    APP[b * 512 + tid]       = feats[b * 512 + tid] * e0 * inv;
    APP[b * 512 + tid + 256] = feats[b * 512 + tid + 256] * e1 * inv;
}

// ---------------- per-step: GRU gates + h update ----------------------------------
__global__ __launch_bounds__(256) void gru_gate(
    const float* __restrict__ GX, const float* __restrict__ AB,
    const float* __restrict__ hprev, float* __restrict__ hs_t,
    unsigned short* __restrict__ hsb_t)
{
    int i = blockIdx.x * 256 + threadIdx.x;    // 65536
    int b = i >> 9, n = i & 511;
    float xr = GX[b * 1536 + n];
    float xz = GX[b * 1536 + 512 + n];
    float xn = GX[b * 1536 + 1024 + n];
    float hr = AB[b * 2048 + 512 + n];
    float hz = AB[b * 2048 + 1024 + n];
    float hn = AB[b * 2048 + 1536 + n];
    float r = 1.f / (1.f + __expf(-(xr + hr)));
    float z = 1.f / (1.f + __expf(-(xz + hz)));
    float nt = tanhf(xn + r * hn);
    float h = (1.f - z) * nt + z * hprev[i];
    hs_t[i] = h;
    hsb_t[i] = f2bf(h);
}

// ---------------- output GEMM: logits = HSb @ outWb^T + out_b (bf16 MFMA) ----------
// A [8192,512] bf16 row-major, B [10000,512] bf16 row-major, C fp32 [8192,10000].
// 128x128 tile, BK=32, 4 waves each computing a 64x64 quadrant of 16x16x32 MFMAs.
__global__ __launch_bounds__(256) void gemm_out_bf16(
    const unsigned short* __restrict__ A, const unsigned short* __restrict__ Bw,
    const float* __restrict__ bias, float* __restrict__ C, int N)
{
    __shared__ __align__(16) unsigned short As[128 * 32];
    __shared__ __align__(16) unsigned short Bs[128 * 32];
    const int tid = threadIdx.x;
    const int lane = tid & 63, wave = tid >> 6;
    const int bm = blockIdx.y * 128, bn = blockIdx.x * 128;
    const int wm = (wave & 1) * 64, wn = (wave >> 1) * 64;
    const int sr = tid >> 2, sc = (tid & 3) * 8;
    const int m16 = lane & 15, q = lane >> 4;

    f32x4_t acc[4][4];
#pragma unroll
    for (int i = 0; i < 4; i++)
#pragma unroll
        for (int j = 0; j < 4; j++)
            acc[i][j] = (f32x4_t){0.f, 0.f, 0.f, 0.f};

    for (int kc = 0; kc < 512; kc += 32) {
        uint4 a0 = *(const uint4*)(A + (size_t)(bm + sr) * 512 + kc + sc);
        uint4 a1 = *(const uint4*)(A + (size_t)(bm + 64 + sr) * 512 + kc + sc);
        uint4 b0, b1;
        int rb0 = bn + sr, rb1 = bn + 64 + sr;
        if (rb0 < N) b0 = *(const uint4*)(Bw + (size_t)rb0 * 512 + kc + sc);
        else { b0.x = 0; b0.y = 0; b0.z = 0; b0.w = 0; }
        if (rb1 < N) b1 = *(const uint4*)(Bw + (size_t)rb1 * 512 + kc + sc);
        else { b1.x = 0; b1.y = 0; b1.z = 0; b1.w = 0; }
        __syncthreads();
        *(uint4*)(&As[sr * 32 + sc]) = a0;
        *(uint4*)(&As[(sr + 64) * 32 + sc]) = a1;
        *(uint4*)(&Bs[sr * 32 + sc]) = b0;
        *(uint4*)(&Bs[(sr + 64) * 32 + sc]) = b1;
        __syncthreads();

        s16x8_t af[4], bf[4];
#pragma unroll
        for (int i = 0; i < 4; i++) {
            af[i] = *(const s16x8_t*)(&As[(wm + i * 16 + m16) * 32 + q * 8]);
            bf[i] = *(const s16x8_t*)(&Bs[(wn + i * 16 + m16) * 32 + q * 8]);
        }
#pragma unroll
        for (int i = 0; i < 4; i++)
#pragma unroll
            for (int j = 0; j < 4; j++)
                acc[i][j] = __builtin_amdgcn_mfma_f32_16x16x32_bf16(af[i], bf[j], acc[i][j], 0, 0, 0);
    }

#pragma unroll
    for (int i = 0; i < 4; i++)
#pragma unroll
        for (int j = 0; j < 4; j++) {
            int gr = bm + wm + i * 16 + q * 4;
            int gc = bn + wn + j * 16 + m16;
            if (gc < N) {
                float bb = bias[gc];
#pragma unroll
                for (int rr = 0; rr < 4; rr++)
                    C[(size_t)(gr + rr) * N + gc] = acc[i][j][rr] + bb;
            }
        }
}

// ---------------- log-softmax: per-row logsumexp, then in-place subtract ----------
__global__ __launch_bounds__(256) void row_lse(const float* __restrict__ C, float* __restrict__ lse)
{
    int row = blockIdx.x, tid = threadIdx.x;
    const float* p = C + (size_t)row * VV;
    float m = -1e30f;
    for (int i = tid; i < VV; i += 256) m = fmaxf(m, p[i]);
    __shared__ float red[256];
    red[tid] = m;
    __syncthreads();
    for (int s = 128; s > 0; s >>= 1) {
        if (tid < s) red[tid] = fmaxf(red[tid], red[tid + s]);
        __syncthreads();
    }
    float mx = red[0];
    __syncthreads();
    float ssum = 0.f;
    for (int i = tid; i < VV; i += 256) ssum += __expf(p[i] - mx);
    red[tid] = ssum;
    __syncthreads();
    for (int s = 128; s > 0; s >>= 1) {
        if (tid < s) red[tid] += red[tid + s];
        __syncthreads();
    }
    if (tid == 0) lse[row] = mx + logf(red[0]);
}

__global__ void sub_lse(float* __restrict__ C, const float* __restrict__ lse)
{
    int i = blockIdx.x * 256 + threadIdx.x;    // 20,480,000 float4
    float l = lse[i / 2500];
    float4 v = ((float4*)C)[i];
    v.x -= l; v.y -= l; v.z -= l; v.w -= l;
    ((float4*)C)[i] = v;
}

// ---------------- hiddens: [T,B,H] -> [B,T,H] -------------------------------------
__global__ void copy_hiddens(const float* __restrict__ HS, float* __restrict__ out)
{
    int id = blockIdx.x * 256 + threadIdx.x;   // 1,048,576 float4
    int h4 = id & 127;
    int t = (id >> 7) & 63;
    int b = id >> 13;
    ((float4*)out)[id] = ((const float4*)HS)[t * 16384 + b * 128 + h4];
}

// ===================================================================================
extern "C" void kernel_launch(void* const* d_in, const int* in_sizes, int n_in,
                              void* d_out, int out_size, void* d_ws, size_t ws_size,
                              hipStream_t stream)
{
    const float* features = (const float*)d_in[0];
    const int*   captions = (const int*)d_in[1];
    const float* h0       = (const float*)d_in[2];
    const float* embed_W  = (const float*)d_in[4];
    const float* fc_W     = (const float*)d_in[5];
    const float* fc_b     = (const float*)d_in[6];
    const float* bn_gamma = (const float*)d_in[7];
    const float* bn_beta  = (const float*)d_in[8];
    const float* attn_W   = (const float*)d_in[9];
    const float* attn_b   = (const float*)d_in[10];
    const float* comb_W   = (const float*)d_in[11];
    const float* comb_b   = (const float*)d_in[12];
    const float* gru_Wih  = (const float*)d_in[13];
    const float* gru_Whh  = (const float*)d_in[14];
    const float* gru_bih  = (const float*)d_in[15];
    const float* gru_bhh  = (const float*)d_in[16];
    const float* out_W    = (const float*)d_in[17];
    const float* out_b    = (const float*)d_in[18];
    float* dout = (float*)d_out;

    // workspace layout (float offsets)
    float* w      = (float*)d_ws;
    float* f      = w;                   //   65,536
    float* feats  = w + 65536;           //   65,536
    float* X      = w + 131072;          // 4,194,304  [T*B, E]
    float* Lx     = w + 4325376;         // 4,194,304  [T*B, H]
    float* Cx     = w + 8519680;         // 4,194,304  [T*B, H]
    float* GxX    = w + 12713984;        // 12,582,912 [T*B, 3H]
    float* HS     = w + 25296896;        // 4,194,304  [T, B, H]
    float* Wcat   = w + 29491200;        // 1,048,576  [2048, 512]
    float* WaT    = w + 30539776;        //   262,144  [512, 512]
    float* W_ac   = w + 30801920;        //   786,432  [1536, 512]
    float* AB     = w + 31588352;        //   262,144  [128, 2048] (L | gh)
    float* APP    = w + 31850496;        //    65,536  [128, 512]
    float* GX     = w + 31916032;        //   196,608  [128, 1536]
    float* lse    = w + 32112640;        //     8,192
    unsigned short* HSb   = (unsigned short*)(w + 32120832); // 4,194,304 ushort
    unsigned short* outWb = (unsigned short*)(w + 34217984); // 5,120,000 ushort

    dim3 blk2(16, 16);

    // ---- prep ----
    // f = features @ fc_W^T + fc_b
    gemm32<<<dim3(16, 4), blk2, 0, stream>>>(features, FIN, fc_W, FIN, 0,
                                             f, EE, FIN, fc_b, nullptr, 0, 0);
    bn_kernel<<<512, 128, 0, stream>>>(f, bn_gamma, bn_beta, feats);
    build_x<<<4096, 256, 0, stream>>>(feats, embed_W, captions, X);
    // Lx = X @ attn_W[:, :512]^T + attn_b
    gemm32<<<dim3(16, 256), blk2, 0, stream>>>(X, EE, attn_W, 1024, 0,
                                               Lx, HH, EE, attn_b, nullptr, 0, 0);
    // Cx = X @ comb_W[:, :512]^T + comb_b
    gemm32<<<dim3(16, 256), blk2, 0, stream>>>(X, EE, comb_W, 1024, 0,
                                               Cx, HH, EE, comb_b, nullptr, 0, 0);
    // GxX = Cx @ Wih^T + bih
    gemm32<<<dim3(48, 256), blk2, 0, stream>>>(Cx, HH, gru_Wih, HH, 0,
                                               GxX, 1536, HH, gru_bih, nullptr, 0, 0);
    transpose_wa<<<1024, 256, 0, stream>>>(comb_W, WaT);
    // W_ac = Wih @ WaT^T   (= Wih @ comb_Wa)
    gemm32<<<dim3(16, 48), blk2, 0, stream>>>(gru_Wih, HH, WaT, HH, 0,
                                              W_ac, HH, HH, nullptr, nullptr, 0, 0);
    pack_wcat<<<4096, 256, 0, stream>>>(attn_W, gru_Whh, Wcat);
    cvt_bf16<<<20000, 256, 0, stream>>>(out_W, outWb, VV * HH);

    // ---- recurrence ----
    for (int t = 0; t < TT; t++) {
        const float* hprev = (t == 0) ? h0 : (HS + (size_t)(t - 1) * BB * HH);
        // AB = [ Lx_t + h@attn_Wh^T  |  bhh + h@Whh^T ]
        gemm32<<<dim3(64, 4), blk2, 0, stream>>>(hprev, HH, Wcat, HH, 0,
                                                 AB, 2048, HH, gru_bhh,
                                                 Lx + (size_t)t * BB * HH, 0, 1);
        softmax_applied<<<128, 256, 0, stream>>>(AB, feats, APP);
        // GX = GxX_t + APP @ W_ac^T
        gemm32<<<dim3(48, 4), blk2, 0, stream>>>(APP, HH, W_ac, HH, 0,
                                                 GX, 1536, HH, nullptr,
                                                 GxX + (size_t)t * BB * 1536, 1536, 0);
        gru_gate<<<256, 256, 0, stream>>>(GX, AB, hprev,
                                          HS + (size_t)t * BB * HH,
                                          HSb + (size_t)t * BB * HH);
    }

    // ---- output head ----
    gemm_out_bf16<<<dim3(79, 64), 256, 0, stream>>>(HSb, outWb, out_b, dout, VV);
    row_lse<<<8192, 256, 0, stream>>>(dout, lse);
    sub_lse<<<80000, 256, 0, stream>>>(dout, lse);
    copy_hiddens<<<4096, 256, 0, stream>>>(HS, dout + (size_t)TT * BB * VV);
}

// Round 2
// 2731.342 us; speedup vs baseline: 1.4885x; 1.4885x over previous
//
#include <hip/hip_runtime.h>

// Model dims
#define BB 128
#define TT 64
#define EE 512
#define HH 512
#define VV 10000
#define FIN 2048

typedef __attribute__((ext_vector_type(4))) float f32x4_t;
typedef __attribute__((ext_vector_type(8))) short s16x8_t;

__device__ __forceinline__ unsigned short f2bf(float x) {
    unsigned int u = __float_as_uint(x);
    unsigned int r = (u + 0x7fffu + ((u >> 16) & 1u)) >> 16;
    return (unsigned short)r;
}

// ---------------- fp32 GEMM (fc layer only): C[M,N] = A[M,K] @ B[N,K]^T + bias -----
__global__ __launch_bounds__(256) void gemm32(
    const float* __restrict__ A, int lda,
    const float* __restrict__ Bw, int ldb,
    float* __restrict__ C, int ldc, int K,
    const float* __restrict__ bias)
{
    __shared__ float As[32][34];
    __shared__ float Bs[32][34];
    const int tx = threadIdx.x, ty = threadIdx.y;
    const int tid = ty * 16 + tx;
    const int m0 = blockIdx.y * 32, n0 = blockIdx.x * 32;
    const int lr = tid >> 3, lc = (tid & 7) << 2;
    const float* ap = A + (size_t)(m0 + lr) * lda + lc;
    const float* bp = Bw + (size_t)(n0 + lr) * ldb + lc;
    float c00 = 0.f, c01 = 0.f, c10 = 0.f, c11 = 0.f;
    for (int kc = 0; kc < K; kc += 32) {
        float4 av = *(const float4*)(ap + kc);
        float4 bv = *(const float4*)(bp + kc);
        __syncthreads();
        As[lc + 0][lr] = av.x; As[lc + 1][lr] = av.y;
        As[lc + 2][lr] = av.z; As[lc + 3][lr] = av.w;
        Bs[lc + 0][lr] = bv.x; Bs[lc + 1][lr] = bv.y;
        Bs[lc + 2][lr] = bv.z; Bs[lc + 3][lr] = bv.w;
        __syncthreads();
#pragma unroll
        for (int kk = 0; kk < 32; kk++) {
            float2 a = *(const float2*)&As[kk][2 * ty];
            float2 b = *(const float2*)&Bs[kk][2 * tx];
            c00 = fmaf(a.x, b.x, c00); c01 = fmaf(a.x, b.y, c01);
            c10 = fmaf(a.y, b.x, c10); c11 = fmaf(a.y, b.y, c11);
        }
    }
    float cc[2][2] = {{c00, c01}, {c10, c11}};
    const int row = m0 + 2 * ty, col = n0 + 2 * tx;
#pragma unroll
    for (int i = 0; i < 2; i++)
#pragma unroll
        for (int j = 0; j < 2; j++)
            C[(size_t)(row + i) * ldc + col + j] = cc[i][j] + bias[col + j];
}

// ---------------- bf16 MFMA GEMM, 128x128 tile ------------------------------------
// C[M,N] = A[M,K]@B[N,K]^T, M%128==0, K%32==0. grid=(ceil(N/128), M/128).
// mode 0: v += bias?bias[c] + base?base[r*ldbase+c]
// mode 1: v += (c<512) ? base[r*512+c] : bias[c-512]
__global__ __launch_bounds__(256) void gemm128(
    const unsigned short* __restrict__ A, const unsigned short* __restrict__ Bw,
    float* __restrict__ C, int N, int K,
    const float* __restrict__ bias,
    const float* __restrict__ base, int ldbase, int mode)
{
    __shared__ __align__(16) unsigned short As[128 * 32];
    __shared__ __align__(16) unsigned short Bs[128 * 32];
    const int tid = threadIdx.x;
    const int lane = tid & 63, wave = tid >> 6;
    const int bm = blockIdx.y * 128, bn = blockIdx.x * 128;
    const int wm = (wave & 1) * 64, wn = (wave >> 1) * 64;
    const int sr = tid >> 2, sc = (tid & 3) * 8;
    const int m16 = lane & 15, q = lane >> 4;

    f32x4_t acc[4][4];
#pragma unroll
    for (int i = 0; i < 4; i++)
#pragma unroll
        for (int j = 0; j < 4; j++)
            acc[i][j] = (f32x4_t){0.f, 0.f, 0.f, 0.f};

    for (int kc = 0; kc < K; kc += 32) {
        uint4 a0 = *(const uint4*)(A + (size_t)(bm + sr) * K + kc + sc);
        uint4 a1 = *(const uint4*)(A + (size_t)(bm + 64 + sr) * K + kc + sc);
        uint4 b0, b1;
        int rb0 = bn + sr, rb1 = bn + 64 + sr;
        if (rb0 < N) b0 = *(const uint4*)(Bw + (size_t)rb0 * K + kc + sc);
        else { b0.x = 0; b0.y = 0; b0.z = 0; b0.w = 0; }
        if (rb1 < N) b1 = *(const uint4*)(Bw + (size_t)rb1 * K + kc + sc);
        else { b1.x = 0; b1.y = 0; b1.z = 0; b1.w = 0; }
        __syncthreads();
        *(uint4*)(&As[sr * 32 + sc]) = a0;
        *(uint4*)(&As[(sr + 64) * 32 + sc]) = a1;
        *(uint4*)(&Bs[sr * 32 + sc]) = b0;
        *(uint4*)(&Bs[(sr + 64) * 32 + sc]) = b1;
        __syncthreads();

        s16x8_t af[4], bf[4];
#pragma unroll
        for (int i = 0; i < 4; i++) {
            af[i] = *(const s16x8_t*)(&As[(wm + i * 16 + m16) * 32 + q * 8]);
            bf[i] = *(const s16x8_t*)(&Bs[(wn + i * 16 + m16) * 32 + q * 8]);
        }
#pragma unroll
        for (int i = 0; i < 4; i++)
#pragma unroll
            for (int j = 0; j < 4; j++)
                acc[i][j] = __builtin_amdgcn_mfma_f32_16x16x32_bf16(af[i], bf[j], acc[i][j], 0, 0, 0);
    }

#pragma unroll
    for (int i = 0; i < 4; i++)
#pragma unroll
        for (int j = 0; j < 4; j++) {
            int gr = bm + wm + i * 16 + q * 4;
            int gc = bn + wn + j * 16 + m16;
            if (gc < N) {
                if (mode == 0) {
                    float addc = bias ? bias[gc] : 0.f;
#pragma unroll
                    for (int rr = 0; rr < 4; rr++) {
                        float v = acc[i][j][rr] + addc;
                        if (base) v += base[(size_t)(gr + rr) * ldbase + gc];
                        C[(size_t)(gr + rr) * N + gc] = v;
                    }
                } else {
#pragma unroll
                    for (int rr = 0; rr < 4; rr++) {
                        int r = gr + rr;
                        float v = acc[i][j][rr];
                        v += (gc < 512) ? base[r * 512 + gc] : bias[gc - 512];
                        C[(size_t)r * N + gc] = v;
                    }
                }
            }
        }
}

// ---------------- bf16 MFMA GEMM, 64x64 tile (latency-optimized, recurrence) -------
// grid=(N/64, M/64). Same epilogue modes.
__global__ __launch_bounds__(256) void gemm64(
    const unsigned short* __restrict__ A, const unsigned short* __restrict__ Bw,
    float* __restrict__ C, int N, int K,
    const float* __restrict__ bias,
    const float* __restrict__ base, int ldbase, int mode)
{
    __shared__ __align__(16) unsigned short As[64 * 32];
    __shared__ __align__(16) unsigned short Bs[64 * 32];
    const int tid = threadIdx.x;
    const int lane = tid & 63, wave = tid >> 6;
    const int bm = blockIdx.y * 64, bn = blockIdx.x * 64;
    const int wm = (wave & 1) * 32, wn = (wave >> 1) * 32;
    const int sr = tid >> 2, sc = (tid & 3) * 8;
    const int m16 = lane & 15, q = lane >> 4;

    f32x4_t acc[2][2];
#pragma unroll
    for (int i = 0; i < 2; i++)
#pragma unroll
        for (int j = 0; j < 2; j++)
            acc[i][j] = (f32x4_t){0.f, 0.f, 0.f, 0.f};

    for (int kc = 0; kc < K; kc += 32) {
        uint4 a0 = *(const uint4*)(A + (size_t)(bm + sr) * K + kc + sc);
        uint4 b0 = *(const uint4*)(Bw + (size_t)(bn + sr) * K + kc + sc);
        __syncthreads();
        *(uint4*)(&As[sr * 32 + sc]) = a0;
        *(uint4*)(&Bs[sr * 32 + sc]) = b0;
        __syncthreads();

        s16x8_t af[2], bf[2];
#pragma unroll
        for (int i = 0; i < 2; i++) {
            af[i] = *(const s16x8_t*)(&As[(wm + i * 16 + m16) * 32 + q * 8]);
            bf[i] = *(const s16x8_t*)(&Bs[(wn + i * 16 + m16) * 32 + q * 8]);
        }
#pragma unroll
        for (int i = 0; i < 2; i++)
#pragma unroll
            for (int j = 0; j < 2; j++)
                acc[i][j] = __builtin_amdgcn_mfma_f32_16x16x32_bf16(af[i], bf[j], acc[i][j], 0, 0, 0);
    }

#pragma unroll
    for (int i = 0; i < 2; i++)
#pragma unroll
        for (int j = 0; j < 2; j++) {
            int gr = bm + wm + i * 16 + q * 4;
            int gc = bn + wn + j * 16 + m16;
            if (mode == 0) {
                float addc = bias ? bias[gc] : 0.f;
#pragma unroll
                for (int rr = 0; rr < 4; rr++) {
                    float v = acc[i][j][rr] + addc;
                    if (base) v += base[(size_t)(gr + rr) * ldbase + gc];
                    C[(size_t)(gr + rr) * N + gc] = v;
                }
            } else {
#pragma unroll
                for (int rr = 0; rr < 4; rr++) {
                    int r = gr + rr;
                    float v = acc[i][j][rr];
                    v += (gc < 512) ? base[r * 512 + gc] : bias[gc - 512];
                    C[(size_t)r * N + gc] = v;
                }
            }
        }
}

// ---------------- BatchNorm1d (training stats over B=128) --------------------------
__global__ __launch_bounds__(128) void bn_kernel(
    const float* __restrict__ f, const float* __restrict__ gamma,
    const float* __restrict__ beta, float* __restrict__ feats)
{
    int e = blockIdx.x, b = threadIdx.x;
    float v = f[b * EE + e];
    __shared__ float s1[128], s2[128];
    s1[b] = v; s2[b] = v * v;
    __syncthreads();
    for (int s = 64; s > 0; s >>= 1) {
        if (b < s) { s1[b] += s1[b + s]; s2[b] += s2[b + s]; }
        __syncthreads();
    }
    float mu = s1[0] * (1.f / 128.f);
    float var = s2[0] * (1.f / 128.f) - mu * mu;
    float inv = 1.f / sqrtf(var + 1e-5f);
    feats[b * EE + e] = gamma[e] * (v - mu) * inv + beta[e];
}

// ---------------- build Xb[t][b][:] in bf16 ---------------------------------------
__global__ void build_x_bf16(const float* __restrict__ feats, const float* __restrict__ embW,
                             const int* __restrict__ cap, unsigned short* __restrict__ Xb)
{
    int id = blockIdx.x * 256 + threadIdx.x;   // 1,048,576 groups of 4
    int e4 = id & 127;
    int rem = id >> 7;
    int b = rem & 127;
    int t = rem >> 7;
    const float4* src;
    if (t == 0) src = (const float4*)(feats + b * EE) + e4;
    else        src = (const float4*)(embW + (size_t)cap[b * TT + t - 1] * EE) + e4;
    float4 v = *src;
    ushort4 o;
    o.x = f2bf(v.x); o.y = f2bf(v.y); o.z = f2bf(v.z); o.w = f2bf(v.w);
    ((ushort4*)Xb)[(size_t)(t * BB + b) * 128 + e4] = o;
}

// ---------------- weight pack/convert kernels -------------------------------------
__global__ void cvt_bf16(const float* __restrict__ src, unsigned short* __restrict__ dst, int n)
{
    int i = blockIdx.x * 256 + threadIdx.x;
    if (i < n) dst[i] = f2bf(src[i]);
}

// attn_Wxb[n,e] = attn_W[n*1024 + e]
__global__ void pack_attn_wx(const float* __restrict__ attnW, unsigned short* __restrict__ dst)
{
    int i = blockIdx.x * 256 + threadIdx.x;    // 262,144
    int n = i >> 9, e = i & 511;
    dst[i] = f2bf(attnW[n * 1024 + e]);
}

// CxTb[e,n] = comb_W[n*1024 + e]
__global__ void pack_cxt(const float* __restrict__ combW, unsigned short* __restrict__ dst)
{
    int i = blockIdx.x * 256 + threadIdx.x;    // 262,144
    int e = i >> 9, n = i & 511;
    dst[i] = f2bf(combW[n * 1024 + e]);
}

// WaTb[m,n] = comb_W[n*1024 + 512 + m]
__global__ void pack_wat(const float* __restrict__ combW, unsigned short* __restrict__ dst)
{
    int i = blockIdx.x * 256 + threadIdx.x;    // 262,144
    int m = i >> 9, n = i & 511;
    dst[i] = f2bf(combW[n * 1024 + 512 + m]);
}

// Wcatb[j,k]: j<512 -> attn_W[j,512+k]; else Whh[j-512,k]
__global__ void pack_wcat_bf(const float* __restrict__ attnW, const float* __restrict__ Whh,
                             unsigned short* __restrict__ dst)
{
    int i = blockIdx.x * 256 + threadIdx.x;    // 1,048,576
    int j = i >> 9, k = i & 511;
    dst[i] = f2bf((j < 512) ? attnW[j * 1024 + 512 + k]
                            : Whh[(size_t)(j - 512) * 512 + k]);
}

// bias2[j] = bih[j] + dot(Wih[j,:], comb_b)
__global__ void bias2_kernel(const float* __restrict__ Wih, const float* __restrict__ comb_b,
                             const float* __restrict__ bih, float* __restrict__ bias2)
{
    int j = blockIdx.x, lane = threadIdx.x;   // grid 1536, block 64
    float s = 0.f;
    for (int n = lane; n < 512; n += 64) s += Wih[(size_t)j * 512 + n] * comb_b[n];
    for (int o = 32; o > 0; o >>= 1) s += __shfl_down(s, o);
    if (lane == 0) bias2[j] = bih[j] + s;
}

// ---------------- per-step: softmax over L row + applied = feats*aw (bf16 out) -----
__global__ __launch_bounds__(256) void softmax_applied(
    const float* __restrict__ AB, const float* __restrict__ feats,
    unsigned short* __restrict__ APPb)
{
    int b = blockIdx.x, tid = threadIdx.x;
    const float* L = AB + b * 2048;
    float v0 = L[tid], v1 = L[tid + 256];
    __shared__ float red[256];
    red[tid] = fmaxf(v0, v1);
    __syncthreads();
    for (int s = 128; s > 0; s >>= 1) {
        if (tid < s) red[tid] = fmaxf(red[tid], red[tid + s]);
        __syncthreads();
    }
    float mx = red[0];
    __syncthreads();
    float e0 = __expf(v0 - mx), e1 = __expf(v1 - mx);
    red[tid] = e0 + e1;
    __syncthreads();
    for (int s = 128; s > 0; s >>= 1) {
        if (tid < s) red[tid] += red[tid + s];
        __syncthreads();
    }
    float inv = 1.f / red[0];
    APPb[b * 512 + tid]       = f2bf(feats[b * 512 + tid] * e0 * inv);
    APPb[b * 512 + tid + 256] = f2bf(feats[b * 512 + tid + 256] * e1 * inv);
}

// ---------------- per-step: GRU gates + h update ----------------------------------
__global__ __launch_bounds__(256) void gru_gate(
    const float* __restrict__ GX, const float* __restrict__ AB,
    const float* __restrict__ hprev, float* __restrict__ hs_t,
    unsigned short* __restrict__ hsb_t)
{
    int i = blockIdx.x * 256 + threadIdx.x;    // 65536
    int b = i >> 9, n = i & 511;
    float xr = GX[b * 1536 + n];
    float xz = GX[b * 1536 + 512 + n];
    float xn = GX[b * 1536 + 1024 + n];
    float hr = AB[b * 2048 + 512 + n];
    float hz = AB[b * 2048 + 1024 + n];
    float hn = AB[b * 2048 + 1536 + n];
    float r = 1.f / (1.f + __expf(-(xr + hr)));
    float z = 1.f / (1.f + __expf(-(xz + hz)));
    float nt = tanhf(xn + r * hn);
    float h = (1.f - z) * nt + z * hprev[i];
    hs_t[i] = h;
    hsb_t[i] = f2bf(h);
}

// ---------------- log-softmax -----------------------------------------------------
__global__ __launch_bounds__(256) void row_lse(const float* __restrict__ C, float* __restrict__ lse)
{
    int row = blockIdx.x, tid = threadIdx.x;
    const float* p = C + (size_t)row * VV;
    float m = -1e30f;
    for (int i = tid; i < VV; i += 256) m = fmaxf(m, p[i]);
    __shared__ float red[256];
    red[tid] = m;
    __syncthreads();
    for (int s = 128; s > 0; s >>= 1) {
        if (tid < s) red[tid] = fmaxf(red[tid], red[tid + s]);
        __syncthreads();
    }
    float mx = red[0];
    __syncthreads();
    float ssum = 0.f;
    for (int i = tid; i < VV; i += 256) ssum += __expf(p[i] - mx);
    red[tid] = ssum;
    __syncthreads();
    for (int s = 128; s > 0; s >>= 1) {
        if (tid < s) red[tid] += red[tid + s];
        __syncthreads();
    }
    if (tid == 0) lse[row] = mx + logf(red[0]);
}

__global__ void sub_lse(float* __restrict__ C, const float* __restrict__ lse)
{
    int i = blockIdx.x * 256 + threadIdx.x;    // 20,480,000 float4
    float l = lse[i / 2500];
    float4 v = ((float4*)C)[i];
    v.x -= l; v.y -= l; v.z -= l; v.w -= l;
    ((float4*)C)[i] = v;
}

// ---------------- hiddens: [T,B,H] -> [B,T,H] -------------------------------------
__global__ void copy_hiddens(const float* __restrict__ HS, float* __restrict__ out)
{
    int id = blockIdx.x * 256 + threadIdx.x;   // 1,048,576 float4
    int h4 = id & 127;
    int t = (id >> 7) & 63;
    int b = id >> 13;
    ((float4*)out)[id] = ((const float4*)HS)[t * 16384 + b * 128 + h4];
}

// ===================================================================================
extern "C" void kernel_launch(void* const* d_in, const int* in_sizes, int n_in,
                              void* d_out, int out_size, void* d_ws, size_t ws_size,
                              hipStream_t stream)
{
    const float* features = (const float*)d_in[0];
    const int*   captions = (const int*)d_in[1];
    const float* h0       = (const float*)d_in[2];
    const float* embed_W  = (const float*)d_in[4];
    const float* fc_W     = (const float*)d_in[5];
    const float* fc_b     = (const float*)d_in[6];
    const float* bn_gamma = (const float*)d_in[7];
    const float* bn_beta  = (const float*)d_in[8];
    const float* attn_W   = (const float*)d_in[9];
    const float* attn_b   = (const float*)d_in[10];
    const float* comb_W   = (const float*)d_in[11];
    const float* comb_b   = (const float*)d_in[12];
    const float* gru_Wih  = (const float*)d_in[13];
    const float* gru_Whh  = (const float*)d_in[14];
    const float* gru_bih  = (const float*)d_in[15];
    const float* gru_bhh  = (const float*)d_in[16];
    const float* out_W    = (const float*)d_in[17];
    const float* out_b    = (const float*)d_in[18];
    float* dout = (float*)d_out;

    // workspace layout
    float* w      = (float*)d_ws;
    float* f      = w;                    //    65,536
    float* feats  = w + 65536;            //    65,536
    float* Lx     = w + 131072;           // 4,194,304
    float* GxX    = w + 4325376;          // 12,582,912
    float* HS     = w + 16908288;         // 4,194,304
    float* W2     = w + 21102592;         //   786,432
    float* W_ac   = w + 21889024;         //   786,432
    float* AB     = w + 22675456;         //   262,144
    float* GX     = w + 22937600;         //   196,608
    float* bias2  = w + 23134208;         //     1,536
    float* lse    = w + 23135744;         //     8,192
    unsigned short* u      = (unsigned short*)(w + 23143936);
    unsigned short* Xb     = u;             // 4,194,304
    unsigned short* attnWxb= u + 4194304;   //   262,144
    unsigned short* Wihb   = u + 4456448;   //   786,432
    unsigned short* CxTb   = u + 5242880;   //   262,144
    unsigned short* WaTb   = u + 5505024;   //   262,144
    unsigned short* Wcatb  = u + 5767168;   // 1,048,576
    unsigned short* W2b    = u + 6815744;   //   786,432
    unsigned short* W_acb  = u + 7602176;   //   786,432
    unsigned short* outWb  = u + 8388608;   // 5,120,000
    unsigned short* HSb    = u + 13508608;  // 4,194,304
    unsigned short* APPb   = u + 17702912;  //    65,536
    unsigned short* h0b    = u + 17768448;  //    65,536

    dim3 blk2(16, 16);

    // ---- prep ----
    gemm32<<<dim3(16, 4), blk2, 0, stream>>>(features, FIN, fc_W, FIN, f, EE, FIN, fc_b);
    bn_kernel<<<512, 128, 0, stream>>>(f, bn_gamma, bn_beta, feats);
    cvt_bf16<<<256, 256, 0, stream>>>(h0, h0b, BB * HH);
    build_x_bf16<<<4096, 256, 0, stream>>>(feats, embed_W, captions, Xb);
    pack_attn_wx<<<1024, 256, 0, stream>>>(attn_W, attnWxb);
    pack_cxt<<<1024, 256, 0, stream>>>(comb_W, CxTb);
    pack_wat<<<1024, 256, 0, stream>>>(comb_W, WaTb);
    pack_wcat_bf<<<4096, 256, 0, stream>>>(attn_W, gru_Whh, Wcatb);
    cvt_bf16<<<3072, 256, 0, stream>>>(gru_Wih, Wihb, 1536 * 512);
    cvt_bf16<<<20000, 256, 0, stream>>>(out_W, outWb, VV * HH);
    bias2_kernel<<<1536, 64, 0, stream>>>(gru_Wih, comb_b, gru_bih, bias2);

    // Lx = X @ attn_Wx^T + attn_b        [8192, 512]
    gemm128<<<dim3(4, 64), 256, 0, stream>>>(Xb, attnWxb, Lx, 512, 512,
                                             attn_b, nullptr, 0, 0);
    // W2 = Wih @ comb_Wx                  [1536, 512]
    gemm64<<<dim3(8, 24), 256, 0, stream>>>(Wihb, CxTb, W2, 512, 512,
                                            nullptr, nullptr, 0, 0);
    cvt_bf16<<<3072, 256, 0, stream>>>(W2, W2b, 1536 * 512);
    // GxX = X @ W2^T + bias2              [8192, 1536]
    gemm128<<<dim3(12, 64), 256, 0, stream>>>(Xb, W2b, GxX, 1536, 512,
                                              bias2, nullptr, 0, 0);
    // W_ac = Wih @ comb_Wa                [1536, 512]
    gemm64<<<dim3(8, 24), 256, 0, stream>>>(Wihb, WaTb, W_ac, 512, 512,
                                            nullptr, nullptr, 0, 0);
    cvt_bf16<<<3072, 256, 0, stream>>>(W_ac, W_acb, 1536 * 512);

    // ---- recurrence ----
    for (int t = 0; t < TT; t++) {
        const unsigned short* hb = (t == 0) ? h0b : (HSb + (size_t)(t - 1) * BB * HH);
        const float* hprev = (t == 0) ? h0 : (HS + (size_t)(t - 1) * BB * HH);
        // AB = [ Lx_t + h@attn_Wh^T  |  bhh + h@Whh^T ]   [128, 2048]
        gemm64<<<dim3(32, 2), 256, 0, stream>>>(hb, Wcatb, AB, 2048, 512,
                                                gru_bhh, Lx + (size_t)t * BB * HH, 512, 1);
        softmax_applied<<<128, 256, 0, stream>>>(AB, feats, APPb);
        // GX = GxX_t + APP @ W_ac^T       [128, 1536]
        gemm64<<<dim3(24, 2), 256, 0, stream>>>(APPb, W_acb, GX, 1536, 512,
                                                nullptr, GxX + (size_t)t * BB * 1536, 1536, 0);
        gru_gate<<<256, 256, 0, stream>>>(GX, AB, hprev,
                                          HS + (size_t)t * BB * HH,
                                          HSb + (size_t)t * BB * HH);
    }

    // ---- output head ----
    gemm128<<<dim3(79, 64), 256, 0, stream>>>(HSb, outWb, dout, VV, 512,
                                              out_b, nullptr, 0, 0);
    row_lse<<<8192, 256, 0, stream>>>(dout, lse);
    sub_lse<<<80000, 256, 0, stream>>>(dout, lse);
    copy_hiddens<<<4096, 256, 0, stream>>>(HS, dout + (size_t)TT * BB * VV);
}